// Round 4
// baseline (203.355 us; speedup 1.0000x reference)
//
#include <hip/hip_runtime.h>
#include <hip/hip_bf16.h>
#include <stdint.h>
#include <stddef.h>

typedef __bf16 bf16;
typedef bf16 bf16x8 __attribute__((ext_vector_type(8)));
typedef float f32x4 __attribute__((ext_vector_type(4)));

#define EPSN 1e-8f
#define TWO_PI 6.283185307179586f

#define NB 16384   // batch
#define NH 512     // hidden
#define NI 256     // input
#define KTOT 1280  // 512 + 512 + 256
#define NKT 20     // K-tiles of 64

__device__ __forceinline__ float2 cmul(float2 a, float2 b) {
  return make_float2(a.x * b.x - a.y * b.y, a.x * b.y + a.y * b.x);
}
// a * conj(b)
__device__ __forceinline__ float2 cmulconj(float2 a, float2 b) {
  return make_float2(a.x * b.x + a.y * b.y, a.y * b.x - a.x * b.y);
}
__device__ __forceinline__ float2 cadd(float2 a, float2 b) {
  return make_float2(a.x + b.x, a.y + b.y);
}
__device__ __forceinline__ int brev9(int i) {
  return (int)(__brev((unsigned)i) >> 23);
}

// async global->LDS, 16B per lane; lds dest = wave-uniform base + lane*16
__device__ __forceinline__ void gload16(const bf16* g, bf16* l) {
  __builtin_amdgcn_global_load_lds(
      (const __attribute__((address_space(1))) void*)g,
      (__attribute__((address_space(3))) void*)l, 16, 0, 0);
}

// ---------------------------------------------------------------------------
// prep: unchanged from the verified 200µs kernel.
// blocks [0,512) = build_U column j; blocks [512, 10752) = pack_A octets.
// ---------------------------------------------------------------------------
__global__ __launch_bounds__(256) void prep(
    const float* __restrict__ ang, const float* __restrict__ rre,
    const float* __restrict__ rim, const float* __restrict__ wre,
    const float* __restrict__ wim, const int* __restrict__ perm,
    const float* __restrict__ hxre, const float* __restrict__ hxim,
    const float* __restrict__ x, bf16* __restrict__ Bm,
    bf16* __restrict__ Apack) {
  __shared__ float2 bufA[512];
  __shared__ float2 bufB[512];
  __shared__ float2 redw[4];
  __shared__ float2 bc;
  __shared__ float2 red2[256];

  const int bid = blockIdx.x;
  const int t = threadIdx.x;

  if (bid >= 512) {
    // ---------------- pack_A ----------------
    const int tid = (bid - 512) * 256 + t;  // 0 .. 16384*160-1
    const int b = tid / 160;
    const int o = tid - b * 160;
    const float* src;
    if (o < 64)
      src = hxre + (size_t)b * 512 + o * 8;
    else if (o < 128)
      src = hxim + (size_t)b * 512 + (o - 64) * 8;
    else
      src = x + (size_t)b * 256 + (o - 128) * 8;
    float4 f0 = ((const float4*)src)[0];
    float4 f1 = ((const float4*)src)[1];
    bf16x8 v;
    v[0] = (bf16)f0.x; v[1] = (bf16)f0.y; v[2] = (bf16)f0.z; v[3] = (bf16)f0.w;
    v[4] = (bf16)f1.x; v[5] = (bf16)f1.y; v[6] = (bf16)f1.z; v[7] = (bf16)f1.w;
    *(bf16x8*)(Apack + (size_t)b * KTOT + o * 8) = v;
    return;
  }

  // ---------------- build_U for column j = bid ----------------
  const int j = bid;
  const int j0 = t, j1 = t + 256;

  const float r1x0 = rre[j0], r1y0 = rim[j0];
  const float r1x1 = rre[j1], r1y1 = rim[j1];
  const float r2x0 = rre[512 + j0], r2y0 = rim[512 + j0];
  const float r2x1 = rre[512 + j1], r2y1 = rim[512 + j1];
  red2[t] = make_float2(r1x0 * r1x0 + r1y0 * r1y0 + r1x1 * r1x1 + r1y1 * r1y1,
                        r2x0 * r2x0 + r2y0 * r2y0 + r2x1 * r2x1 + r2y1 * r2y1);
  __syncthreads();
  for (int off = 128; off > 0; off >>= 1) {
    if (t < off) {
      red2[t].x += red2[t + off].x;
      red2[t].y += red2[t + off].y;
    }
    __syncthreads();
  }
  const float inv1 = 1.0f / (sqrtf(red2[0].x) + EPSN);
  const float inv2 = 1.0f / (sqrtf(red2[0].y) + EPSN);
  const float2 v1a = make_float2(r1x0 * inv1, r1y0 * inv1);
  const float2 v1b = make_float2(r1x1 * inv1, r1y1 * inv1);
  const float2 v2a = make_float2(r2x0 * inv2, r2y0 * inv2);
  const float2 v2b = make_float2(r2x1 * inv2, r2y1 * inv2);

  {
    float sj, cj;
    __sincosf(ang[j], &sj, &cj);
    const float2 dj = make_float2(cj, sj);
    float2 z = make_float2(0.f, 0.f);
    bufA[brev9(j0)] = (j0 == j) ? dj : z;
    bufA[brev9(j1)] = (j1 == j) ? dj : z;
  }
  __syncthreads();

#pragma unroll
  for (int st = 0; st < 9; ++st) {
    const int half = 1 << st;
    const int pos = t & (half - 1);
    const int i0 = ((t >> st) << (st + 1)) + pos;
    const int i1 = i0 + half;
    const float angv = -TWO_PI * (float)pos / (float)(2 << st);
    float sn, cs;
    __sincosf(angv, &sn, &cs);
    float2 u = bufA[i0];
    float2 w = bufA[i1];
    float2 tw = make_float2(cs * w.x - sn * w.y, cs * w.y + sn * w.x);
    bufA[i0] = make_float2(u.x + tw.x, u.y + tw.y);
    bufA[i1] = make_float2(u.x - tw.x, u.y - tw.y);
    __syncthreads();
  }

  {
    float2 p = cadd(cmul(bufA[j0], v1a), cmul(bufA[j1], v1b));
    for (int off = 32; off > 0; off >>= 1) {
      p.x += __shfl_down(p.x, off);
      p.y += __shfl_down(p.y, off);
    }
    if ((t & 63) == 0) redw[t >> 6] = p;
    __syncthreads();
    if (t == 0) bc = cadd(cadd(redw[0], redw[1]), cadd(redw[2], redw[3]));
    __syncthreads();
  }
  const float2 dot1 = bc;

  {
    float2 c0 = cmulconj(dot1, v1a);
    float2 c1 = cmulconj(dot1, v1b);
    float2 a0 = bufA[j0], a1 = bufA[j1];
    bufA[j0] = make_float2(a0.x - 2.f * c0.x, a0.y - 2.f * c0.y);
    bufA[j1] = make_float2(a1.x - 2.f * c1.x, a1.y - 2.f * c1.y);
  }
  __syncthreads();

  {
    int p0 = perm[j0], p1 = perm[j1];
    float s0, c0, s1, c1;
    __sincosf(ang[512 + j0], &s0, &c0);
    __sincosf(ang[512 + j1], &s1, &c1);
    float2 g0 = cmul(make_float2(c0, s0), bufA[p0]);
    float2 g1 = cmul(make_float2(c1, s1), bufA[p1]);
    bufB[brev9(j0)] = g0;
    bufB[brev9(j1)] = g1;
  }
  __syncthreads();

#pragma unroll
  for (int st = 0; st < 9; ++st) {
    const int half = 1 << st;
    const int pos = t & (half - 1);
    const int i0 = ((t >> st) << (st + 1)) + pos;
    const int i1 = i0 + half;
    const float angv = TWO_PI * (float)pos / (float)(2 << st);
    float sn, cs;
    __sincosf(angv, &sn, &cs);
    float2 u = bufB[i0];
    float2 w = bufB[i1];
    float2 tw = make_float2(cs * w.x - sn * w.y, cs * w.y + sn * w.x);
    bufB[i0] = make_float2(u.x + tw.x, u.y + tw.y);
    bufB[i1] = make_float2(u.x - tw.x, u.y - tw.y);
    __syncthreads();
  }

  {
    float2 q = cadd(cmul(bufB[j0], v2a), cmul(bufB[j1], v2b));
    for (int off = 32; off > 0; off >>= 1) {
      q.x += __shfl_down(q.x, off);
      q.y += __shfl_down(q.y, off);
    }
    if ((t & 63) == 0) redw[t >> 6] = q;
    __syncthreads();
    if (t == 0) bc = cadd(cadd(redw[0], redw[1]), cadd(redw[2], redw[3]));
    __syncthreads();
  }
  const float invN = 1.0f / 512.0f;
  const float2 dot2 = make_float2(bc.x * invN, bc.y * invN);

#pragma unroll
  for (int e = 0; e < 2; ++e) {
    const int i = (e == 0) ? j0 : j1;
    const float2 vj = (e == 0) ? v2a : v2b;
    float2 h2 = make_float2(bufB[i].x * invN, bufB[i].y * invN);
    float2 c2 = cmulconj(dot2, vj);
    float2 hh = make_float2(h2.x - 2.f * c2.x, h2.y - 2.f * c2.y);
    float s3, c3;
    __sincosf(ang[1024 + i], &s3, &c3);
    float2 u = cmul(make_float2(c3, s3), hh);  // U[i][j]
    bf16* r0 = Bm + (size_t)(2 * i) * KTOT;
    bf16* r1 = Bm + (size_t)(2 * i + 1) * KTOT;
    r0[j] = (bf16)u.x;
    r0[512 + j] = (bf16)(-u.y);
    r1[j] = (bf16)u.y;
    r1[512 + j] = (bf16)u.x;
  }

  Bm[(size_t)(2 * j) * KTOT + 1024 + t] = (bf16)wre[j * NI + t];
  Bm[(size_t)(2 * j + 1) * KTOT + 1024 + t] = (bf16)wim[j * NI + t];
}

// ---------------------------------------------------------------------------
// Fused GEMM + ModReLU, 8-phase counted-vmcnt schedule (T2+T3+T4+T5).
// Round-4 change vs the round-2 kernel that RAN: add the m201 pinning —
// after each barrier that precedes a ds_read-consuming MFMA cluster, emit
// `s_waitcnt lgkmcnt(0)` (asm, memory clobber) + sched_barrier(0) (rule #18),
// and order mmq kh-outermost. Barriers stay __builtin_amdgcn_s_barrier()
// (inline-asm s_barrier is non-convergent in LLVM -> can deadlock; rounds
// 1 & 3 both died with it, round 2 ran with the builtin — never asm it).
//
// Geometry (unchanged): 256x256 tile, BK=64, 8 waves (2Mx4N), 128 KiB LDS
// dbuf, grid 256 = 1 block/CU, one round.
// Stage plan per iter (tiles T=2i buf0, T+1 buf1; 1 unit = 2 gload_lds):
//   ph1 Am1(T+1)->b1  ph2 Bn1(T+1)->b1  ph3 Am0(T+2)->b0  ph4 Bn0(T+2)->b0
//   ph5 Am1(T+2)->b0  ph6 Bn1(T+2)->b0  ph7 Am0(T+3)->b1  ph8 Bn0(T+3)->b1
// vmcnt(4) only at ph4/ph8 (never 0 in-loop). Tail prefetch clamped to 19.
// Swizzle: LDS chunk p of row r holds logical chunk p^(r&7); staging
// pre-swizzles the GLOBAL chunk ((lane&7)^(lane>>3)); reads use
// ((kh*4+lq)^(row&7)) -- identical to the verified 0-conflict kernel.
// ---------------------------------------------------------------------------

#define BARM() __builtin_amdgcn_s_barrier()
#define WVM(n) asm volatile("s_waitcnt vmcnt(" #n ")" ::: "memory")
#define LGKM0()                                        \
  do {                                                 \
    asm volatile("s_waitcnt lgkmcnt(0)" ::: "memory"); \
    __builtin_amdgcn_sched_barrier(0);                 \
  } while (0)

// stage unit Am(h) of K-tile kt into A-buffer Asb (rows h*64+wv*8 and +128)
__device__ __forceinline__ void stA(const bf16* gA, bf16* Asb, int wv, int h,
                                    int kt) {
  const int r0 = h * 64 + wv * 8;
  const int r1 = r0 + 128;
  gload16(gA + (size_t)r0 * KTOT + kt * 64, Asb + r0 * 64);
  gload16(gA + (size_t)r1 * KTOT + kt * 64, Asb + r1 * 64);
}
// stage unit Bn(h): rows (u>>2)*64 + h*32 + (u&3)*8, u = wv*2+g
__device__ __forceinline__ void stB(const bf16* gB, bf16* Bsb, int wv, int h,
                                    int kt) {
  const int u0 = wv * 2, u1 = u0 + 1;
  const int r0 = (u0 >> 2) * 64 + h * 32 + (u0 & 3) * 8;
  const int r1 = (u1 >> 2) * 64 + h * 32 + (u1 & 3) * 8;
  gload16(gB + (size_t)r0 * KTOT + kt * 64, Bsb + r0 * 64);
  gload16(gB + (size_t)r1 * KTOT + kt * 64, Bsb + r1 * 64);
}

__device__ __forceinline__ void lda(const bf16* Asb, int rowbase,
                                    const int (&co)[2], bf16x8 (&af)[4][2]) {
#pragma unroll
  for (int mi = 0; mi < 4; ++mi)
#pragma unroll
    for (int kh = 0; kh < 2; ++kh)
      af[mi][kh] = *(const bf16x8*)&Asb[(rowbase + mi * 16) * 64 + co[kh]];
}
__device__ __forceinline__ void ldb(const bf16* Bsb, int rowbase,
                                    const int (&co)[2], bf16x8 (&bb)[2][2]) {
#pragma unroll
  for (int ni = 0; ni < 2; ++ni)
#pragma unroll
    for (int kh = 0; kh < 2; ++kh)
      bb[ni][kh] = *(const bf16x8*)&Bsb[(rowbase + ni * 16) * 64 + co[kh]];
}
// kh OUTERMOST: the 8 dependent kh0->kh1 accumulate pairs are separated by 7
// independent MFMAs -> no back-to-back same-acc dependency stalls.
__device__ __forceinline__ void mmq(const bf16x8 (&af)[4][2],
                                    const bf16x8 (&bb)[2][2],
                                    f32x4 (&acc)[8][4], int mh, int nh) {
  __builtin_amdgcn_s_setprio(1);
#pragma unroll
  for (int kh = 0; kh < 2; ++kh)
#pragma unroll
    for (int mi = 0; mi < 4; ++mi)
#pragma unroll
      for (int ni = 0; ni < 2; ++ni)
        acc[mh * 4 + mi][nh * 2 + ni] = __builtin_amdgcn_mfma_f32_16x16x32_bf16(
            af[mi][kh], bb[ni][kh], acc[mh * 4 + mi][nh * 2 + ni], 0, 0, 0);
  __builtin_amdgcn_s_setprio(0);
}

__global__ __launch_bounds__(512, 2) void gemm_fused(
    const bf16* __restrict__ Apack, const bf16* __restrict__ Bm,
    const float* __restrict__ beta, float* __restrict__ out) {
  __shared__ bf16 As[2][256 * 64];
  __shared__ bf16 Bs[2][256 * 64];

  const int t = threadIdx.x;
  const int lane = t & 63;
  const int wv = t >> 6;  // 0..7

  const int id = blockIdx.x;  // 0..255
  const int xcd = id & 7;
  const int lix = id >> 3;  // 0..31
  const int mBase = (xcd * 8 + (lix >> 2)) * 256;  // 64 M-panels
  const int nBase = (lix & 3) * 256;               // 4 N-panels

  // staging source: per-lane row = +(lane>>3), pre-swizzled chunk
  const int sub = lane >> 3;
  const int chunk = (lane & 7) ^ sub;
  const bf16* gA = Apack + (size_t)(mBase + sub) * KTOT + chunk * 8;
  const bf16* gB = Bm + (size_t)(nBase + sub) * KTOT + chunk * 8;

  const int lr = lane & 15;
  const int lq = lane >> 4;
  const int lrm = lr & 7;
  const int waveM = wv & 1;   // 2 M positions x 128 rows
  const int waveN = wv >> 1;  // 4 N positions x 64 cols

  const int co[2] = {(lq ^ lrm) * 8, ((4 + lq) ^ lrm) * 8};
  const int arow = waveM * 128 + lr;
  const int brow = waveN * 64 + lr;

  f32x4 acc[8][4] = {};
  bf16x8 af[4][2], b0[2][2], b1[2][2];

  // ---- prologue: tile0 (4 units -> buf0), tile1 Am0/Bn0 (-> buf1) ----
  stA(gA, &As[0][0], wv, 0, 0);
  stB(gB, &Bs[0][0], wv, 0, 0);
  stA(gA, &As[0][0], wv, 1, 0);
  stB(gB, &Bs[0][0], wv, 1, 0);
  stA(gA, &As[1][0], wv, 0, 1);
  stB(gB, &Bs[1][0], wv, 0, 1);
  WVM(4);  // tile 0 landed; tile 1's first 2 units in flight
  BARM();

  for (int i = 0; i < 10; ++i) {
    const int t1 = 2 * i + 1;
    const int t2 = (t1 + 1 < NKT) ? t1 + 1 : NKT - 1;
    const int t3 = (t1 + 2 < NKT) ? t1 + 2 : NKT - 1;

    // ================= tile 2i from buf0 =================
    // ph1 (m0,n0)
    lda(&As[0][0], arow, co, af);
    ldb(&Bs[0][0], brow, co, b0);
    stA(gA, &As[1][0], wv, 1, t1);  // Am1(T+1) -> buf1
    BARM();
    LGKM0();
    mmq(af, b0, acc, 0, 0);
    BARM();
    // ph2 (m0,n1)
    ldb(&Bs[0][0], brow + 32, co, b1);
    stB(gB, &Bs[1][0], wv, 1, t1);  // Bn1(T+1) -> buf1
    BARM();
    LGKM0();
    mmq(af, b1, acc, 0, 1);
    BARM();
    // ph3 (m1,n0)
    lda(&As[0][0], arow + 64, co, af);
    stA(gA, &As[0][0], wv, 0, t2);  // Am0(T+2) -> buf0
    BARM();
    LGKM0();
    mmq(af, b0, acc, 1, 0);
    BARM();
    // ph4 (m1,n1) — no new ds_reads; operands waited at ph3's LGKM0
    stB(gB, &Bs[0][0], wv, 0, t2);  // Bn0(T+2) -> buf0
    BARM();
    mmq(af, b1, acc, 1, 1);
    WVM(4);  // tile T+1 fully landed (outstanding = ph3+ph4 units)
    BARM();

    // ================= tile 2i+1 from buf1 =================
    // ph5 (m0,n0)
    lda(&As[1][0], arow, co, af);
    ldb(&Bs[1][0], brow, co, b0);
    stA(gA, &As[0][0], wv, 1, t2);  // Am1(T+2) -> buf0
    BARM();
    LGKM0();
    mmq(af, b0, acc, 0, 0);
    BARM();
    // ph6 (m0,n1)
    ldb(&Bs[1][0], brow + 32, co, b1);
    stB(gB, &Bs[0][0], wv, 1, t2);  // Bn1(T+2) -> buf0
    BARM();
    LGKM0();
    mmq(af, b1, acc, 0, 1);
    BARM();
    // ph7 (m1,n0)
    lda(&As[1][0], arow + 64, co, af);
    stA(gA, &As[1][0], wv, 0, t3);  // Am0(T+3) -> buf1
    BARM();
    LGKM0();
    mmq(af, b0, acc, 1, 0);
    BARM();
    // ph8 (m1,n1) — no new ds_reads
    stB(gB, &Bs[1][0], wv, 0, t3);  // Bn0(T+3) -> buf1
    BARM();
    mmq(af, b1, acc, 1, 1);
    WVM(4);  // tile T+2 fully landed (outstanding = ph7+ph8 units)
    BARM();
  }
  WVM(0);  // drain tail re-stages before epilogue

  // Epilogue: C layout col=lane&15, row=lq*4+r. Physical col n: even=re,
  // odd=im of h=n>>1; col parity == lane parity -> shfl_xor(1) pairs them.
  const int col = lane & 15;
  const int row0 = lq * 4;
  const int parity = lane & 1;
#pragma unroll
  for (int nq = 0; nq < 4; ++nq) {
    const int n = nBase + waveN * 64 + nq * 16 + col;
    const float bet = beta[n >> 1];
#pragma unroll
    for (int mq = 0; mq < 8; ++mq) {
      const int mrow = mBase + waveM * 128 + mq * 16 + row0;
#pragma unroll
      for (int r = 0; r < 4; ++r) {
        float a = acc[mq][nq][r];
        float o = __shfl_xor(a, 1);
        float re = parity ? o : a;
        float im = parity ? a : o;
        float mag2 = re * re + im * im;
        float val;
        if (mag2 > 0.f) {
          float rs = __frsqrt_rn(mag2);  // 1/mag
          float s = mag2 * rs + bet;     // mag + beta
          val = (s > 0.f) ? (parity ? im : re) * (s * rs) : 0.f;
        } else {
          val = (bet > 0.f && parity == 0) ? bet : 0.f;  // angle(0)==0
        }
        out[(size_t)(mrow + r) * 1024 + n] = val;
      }
    }
  }
}

// ---------------------------------------------------------------------------
extern "C" void kernel_launch(void* const* d_in, const int* in_sizes, int n_in,
                              void* d_out, int out_size, void* d_ws,
                              size_t ws_size, hipStream_t stream) {
  const float* x = (const float*)d_in[0];
  const float* hxre = (const float*)d_in[1];
  const float* hxim = (const float*)d_in[2];
  const float* ang = (const float*)d_in[3];
  const float* rre = (const float*)d_in[4];
  const float* rim = (const float*)d_in[5];
  const float* wre = (const float*)d_in[6];
  const float* wim = (const float*)d_in[7];
  const float* beta = (const float*)d_in[8];
  const int* perm = (const int*)d_in[9];

  char* ws = (char*)d_ws;
  bf16* Bm = (bf16*)ws;                                 // 1024x1280 bf16, 2.5 MiB
  bf16* Apack = (bf16*)(ws + (size_t)1024 * KTOT * 2);  // 16384x1280 bf16, 40 MiB

  prep<<<512 + (NB * 160) / 256, 256, 0, stream>>>(ang, rre, rim, wre, wim,
                                                   perm, hxre, hxim, x, Bm,
                                                   Apack);
  gemm_fused<<<256, 512, 0, stream>>>(Apack, Bm, beta, (float*)d_out);
}

// Round 5
// 201.283 us; speedup vs baseline: 1.0103x; 1.0103x over previous
//
#include <hip/hip_runtime.h>
#include <hip/hip_bf16.h>
#include <stdint.h>
#include <stddef.h>

typedef __bf16 bf16;
typedef bf16 bf16x8 __attribute__((ext_vector_type(8)));
typedef float f32x4 __attribute__((ext_vector_type(4)));

#define EPSN 1e-8f
#define TWO_PI 6.283185307179586f

#define NB 16384   // batch
#define NH 512     // hidden
#define NI 256     // input
#define KTOT 1280  // 512 + 512 + 256
#define NKT 20     // K-tiles of 64

__device__ __forceinline__ float2 cmul(float2 a, float2 b) {
  return make_float2(a.x * b.x - a.y * b.y, a.x * b.y + a.y * b.x);
}
// a * conj(b)
__device__ __forceinline__ float2 cmulconj(float2 a, float2 b) {
  return make_float2(a.x * b.x + a.y * b.y, a.y * b.x - a.x * b.y);
}
__device__ __forceinline__ float2 cadd(float2 a, float2 b) {
  return make_float2(a.x + b.x, a.y + b.y);
}
__device__ __forceinline__ int brev9(int i) {
  return (int)(__brev((unsigned)i) >> 23);
}

// async global->LDS, 16B per lane; lds dest = wave-uniform base + lane*16
__device__ __forceinline__ void gload16(const bf16* g, bf16* l) {
  __builtin_amdgcn_global_load_lds(
      (const __attribute__((address_space(1))) void*)g,
      (__attribute__((address_space(3))) void*)l, 16, 0, 0);
}

// ---------------------------------------------------------------------------
// prep: unchanged from the verified 200µs kernel.
// blocks [0,512) = build_U column j; blocks [512, 10752) = pack_A octets.
// ---------------------------------------------------------------------------
__global__ __launch_bounds__(256) void prep(
    const float* __restrict__ ang, const float* __restrict__ rre,
    const float* __restrict__ rim, const float* __restrict__ wre,
    const float* __restrict__ wim, const int* __restrict__ perm,
    const float* __restrict__ hxre, const float* __restrict__ hxim,
    const float* __restrict__ x, bf16* __restrict__ Bm,
    bf16* __restrict__ Apack) {
  __shared__ float2 bufA[512];
  __shared__ float2 bufB[512];
  __shared__ float2 redw[4];
  __shared__ float2 bc;
  __shared__ float2 red2[256];

  const int bid = blockIdx.x;
  const int t = threadIdx.x;

  if (bid >= 512) {
    // ---------------- pack_A ----------------
    const int tid = (bid - 512) * 256 + t;  // 0 .. 16384*160-1
    const int b = tid / 160;
    const int o = tid - b * 160;
    const float* src;
    if (o < 64)
      src = hxre + (size_t)b * 512 + o * 8;
    else if (o < 128)
      src = hxim + (size_t)b * 512 + (o - 64) * 8;
    else
      src = x + (size_t)b * 256 + (o - 128) * 8;
    float4 f0 = ((const float4*)src)[0];
    float4 f1 = ((const float4*)src)[1];
    bf16x8 v;
    v[0] = (bf16)f0.x; v[1] = (bf16)f0.y; v[2] = (bf16)f0.z; v[3] = (bf16)f0.w;
    v[4] = (bf16)f1.x; v[5] = (bf16)f1.y; v[6] = (bf16)f1.z; v[7] = (bf16)f1.w;
    *(bf16x8*)(Apack + (size_t)b * KTOT + o * 8) = v;
    return;
  }

  // ---------------- build_U for column j = bid ----------------
  const int j = bid;
  const int j0 = t, j1 = t + 256;

  const float r1x0 = rre[j0], r1y0 = rim[j0];
  const float r1x1 = rre[j1], r1y1 = rim[j1];
  const float r2x0 = rre[512 + j0], r2y0 = rim[512 + j0];
  const float r2x1 = rre[512 + j1], r2y1 = rim[512 + j1];
  red2[t] = make_float2(r1x0 * r1x0 + r1y0 * r1y0 + r1x1 * r1x1 + r1y1 * r1y1,
                        r2x0 * r2x0 + r2y0 * r2y0 + r2x1 * r2x1 + r2y1 * r2y1);
  __syncthreads();
  for (int off = 128; off > 0; off >>= 1) {
    if (t < off) {
      red2[t].x += red2[t + off].x;
      red2[t].y += red2[t + off].y;
    }
    __syncthreads();
  }
  const float inv1 = 1.0f / (sqrtf(red2[0].x) + EPSN);
  const float inv2 = 1.0f / (sqrtf(red2[0].y) + EPSN);
  const float2 v1a = make_float2(r1x0 * inv1, r1y0 * inv1);
  const float2 v1b = make_float2(r1x1 * inv1, r1y1 * inv1);
  const float2 v2a = make_float2(r2x0 * inv2, r2y0 * inv2);
  const float2 v2b = make_float2(r2x1 * inv2, r2y1 * inv2);

  {
    float sj, cj;
    __sincosf(ang[j], &sj, &cj);
    const float2 dj = make_float2(cj, sj);
    float2 z = make_float2(0.f, 0.f);
    bufA[brev9(j0)] = (j0 == j) ? dj : z;
    bufA[brev9(j1)] = (j1 == j) ? dj : z;
  }
  __syncthreads();

#pragma unroll
  for (int st = 0; st < 9; ++st) {
    const int half = 1 << st;
    const int pos = t & (half - 1);
    const int i0 = ((t >> st) << (st + 1)) + pos;
    const int i1 = i0 + half;
    const float angv = -TWO_PI * (float)pos / (float)(2 << st);
    float sn, cs;
    __sincosf(angv, &sn, &cs);
    float2 u = bufA[i0];
    float2 w = bufA[i1];
    float2 tw = make_float2(cs * w.x - sn * w.y, cs * w.y + sn * w.x);
    bufA[i0] = make_float2(u.x + tw.x, u.y + tw.y);
    bufA[i1] = make_float2(u.x - tw.x, u.y - tw.y);
    __syncthreads();
  }

  {
    float2 p = cadd(cmul(bufA[j0], v1a), cmul(bufA[j1], v1b));
    for (int off = 32; off > 0; off >>= 1) {
      p.x += __shfl_down(p.x, off);
      p.y += __shfl_down(p.y, off);
    }
    if ((t & 63) == 0) redw[t >> 6] = p;
    __syncthreads();
    if (t == 0) bc = cadd(cadd(redw[0], redw[1]), cadd(redw[2], redw[3]));
    __syncthreads();
  }
  const float2 dot1 = bc;

  {
    float2 c0 = cmulconj(dot1, v1a);
    float2 c1 = cmulconj(dot1, v1b);
    float2 a0 = bufA[j0], a1 = bufA[j1];
    bufA[j0] = make_float2(a0.x - 2.f * c0.x, a0.y - 2.f * c0.y);
    bufA[j1] = make_float2(a1.x - 2.f * c1.x, a1.y - 2.f * c1.y);
  }
  __syncthreads();

  {
    int p0 = perm[j0], p1 = perm[j1];
    float s0, c0, s1, c1;
    __sincosf(ang[512 + j0], &s0, &c0);
    __sincosf(ang[512 + j1], &s1, &c1);
    float2 g0 = cmul(make_float2(c0, s0), bufA[p0]);
    float2 g1 = cmul(make_float2(c1, s1), bufA[p1]);
    bufB[brev9(j0)] = g0;
    bufB[brev9(j1)] = g1;
  }
  __syncthreads();

#pragma unroll
  for (int st = 0; st < 9; ++st) {
    const int half = 1 << st;
    const int pos = t & (half - 1);
    const int i0 = ((t >> st) << (st + 1)) + pos;
    const int i1 = i0 + half;
    const float angv = TWO_PI * (float)pos / (float)(2 << st);
    float sn, cs;
    __sincosf(angv, &sn, &cs);
    float2 u = bufB[i0];
    float2 w = bufB[i1];
    float2 tw = make_float2(cs * w.x - sn * w.y, cs * w.y + sn * w.x);
    bufB[i0] = make_float2(u.x + tw.x, u.y + tw.y);
    bufB[i1] = make_float2(u.x - tw.x, u.y - tw.y);
    __syncthreads();
  }

  {
    float2 q = cadd(cmul(bufB[j0], v2a), cmul(bufB[j1], v2b));
    for (int off = 32; off > 0; off >>= 1) {
      q.x += __shfl_down(q.x, off);
      q.y += __shfl_down(q.y, off);
    }
    if ((t & 63) == 0) redw[t >> 6] = q;
    __syncthreads();
    if (t == 0) bc = cadd(cadd(redw[0], redw[1]), cadd(redw[2], redw[3]));
    __syncthreads();
  }
  const float invN = 1.0f / 512.0f;
  const float2 dot2 = make_float2(bc.x * invN, bc.y * invN);

#pragma unroll
  for (int e = 0; e < 2; ++e) {
    const int i = (e == 0) ? j0 : j1;
    const float2 vj = (e == 0) ? v2a : v2b;
    float2 h2 = make_float2(bufB[i].x * invN, bufB[i].y * invN);
    float2 c2 = cmulconj(dot2, vj);
    float2 hh = make_float2(h2.x - 2.f * c2.x, h2.y - 2.f * c2.y);
    float s3, c3;
    __sincosf(ang[1024 + i], &s3, &c3);
    float2 u = cmul(make_float2(c3, s3), hh);  // U[i][j]
    bf16* r0 = Bm + (size_t)(2 * i) * KTOT;
    bf16* r1 = Bm + (size_t)(2 * i + 1) * KTOT;
    r0[j] = (bf16)u.x;
    r0[512 + j] = (bf16)(-u.y);
    r1[j] = (bf16)u.y;
    r1[512 + j] = (bf16)u.x;
  }

  Bm[(size_t)(2 * j) * KTOT + 1024 + t] = (bf16)wre[j * NI + t];
  Bm[(size_t)(2 * j + 1) * KTOT + 1024 + t] = (bf16)wim[j * NI + t];
}

// ---------------------------------------------------------------------------
// Fused GEMM + ModReLU — single-barrier pipelined windows (round 5).
// Round-2's 2-barriers-per-phase lockstep serialized the LDS-read window
// against the MFMA window (MfmaUtil 24%, VALUBusy 17%, both pipes idle 60%).
// Fix: each window = { mmq(frags read LAST window); ds_reads for NEXT mmq;
// stage; BAR } -> one barrier per window (8 per 2 K-tiles, was 16); the
// ds_read/LDS-pipe work and stage issue overlap the MFMA-pipe work.
//
// Geometry unchanged: 256x256 tile, BK=64, 8 waves (2Mx4N), 128 KiB LDS
// dbuf, grid 256 = 1 block/CU. acc[8][4] f32x4; af/b0/b1 frag regs reused
// WAR-style (mmq consumes before the overwriting ds_read issues).
//
// Window plan per iter i (buf0 = tile 2i, buf1 = tile 2i+1; t2/t3 clamped):
//  W1: q00(T)   rd B1(b0f0)      st Bn1(2i+1)->b1 | BAR
//  W2: q01(T)   rd A1(b0f0)      st Am0(t2)->b0   | BAR
//  W3: q10(T)                    st Bn0(t2)->b0   | WVM(4) BAR
//  W4: q11(T)   rd A0,B0(b1f1)   st Am1(t2)->b0   | BAR
//  W5: q00(T+1) rd B1(b1f1)      st Bn1(t2)->b0   | BAR
//  W6: q01(T+1) rd A1(b1f1)      st Am0(t3)->b1   | BAR
//  W7: q10(T+1)                  st Bn0(t3)->b1   | WVM(4) BAR
//  W8: q11(T+1) rd A0,B0(b0f0)   st Am1(t3)->b1   | BAR
// Hazard rule verified: every stage target's last LDS-read is >=2 windows
// earlier (read data is register-landed before the reader's barrier, which
// happens-before the post-barrier stage write). WVM(4) at W3/W7 proves the
// next tile's 4 units landed (oldest 8 of 12 outstanding) before first read.
// Tail: t2/t3 clamped to 19 -> benign re-stages into dead regions; W8(i=9)
// reads are dead. vmcnt never drained to 0 in-loop. Barriers are the
// builtin ONLY (inline-asm s_barrier is non-convergent -> deadlocked twice).
// Swizzle: LDS chunk p of row r holds logical chunk p^(r&7); staging
// pre-swizzles the GLOBAL chunk ((lane&7)^(lane>>3)); reads use
// ((kh*4+lq)^(row&7)) -- identical to the verified 0-conflict kernel.
// ---------------------------------------------------------------------------

#define BARM() __builtin_amdgcn_s_barrier()
#define WVM(n) asm volatile("s_waitcnt vmcnt(" #n ")" ::: "memory")

// stage unit Am(h) of K-tile kt into A-buffer Asb (rows h*64+wv*8 and +128)
__device__ __forceinline__ void stA(const bf16* gA, bf16* Asb, int wv, int h,
                                    int kt) {
  const int r0 = h * 64 + wv * 8;
  const int r1 = r0 + 128;
  gload16(gA + (size_t)r0 * KTOT + kt * 64, Asb + r0 * 64);
  gload16(gA + (size_t)r1 * KTOT + kt * 64, Asb + r1 * 64);
}
// stage unit Bn(h): rows (u>>2)*64 + h*32 + (u&3)*8, u = wv*2+g
__device__ __forceinline__ void stB(const bf16* gB, bf16* Bsb, int wv, int h,
                                    int kt) {
  const int u0 = wv * 2, u1 = u0 + 1;
  const int r0 = (u0 >> 2) * 64 + h * 32 + (u0 & 3) * 8;
  const int r1 = (u1 >> 2) * 64 + h * 32 + (u1 & 3) * 8;
  gload16(gB + (size_t)r0 * KTOT + kt * 64, Bsb + r0 * 64);
  gload16(gB + (size_t)r1 * KTOT + kt * 64, Bsb + r1 * 64);
}

__device__ __forceinline__ void lda(const bf16* Asb, int rowbase,
                                    const int (&co)[2], bf16x8 (&af)[4][2]) {
#pragma unroll
  for (int mi = 0; mi < 4; ++mi)
#pragma unroll
    for (int kh = 0; kh < 2; ++kh)
      af[mi][kh] = *(const bf16x8*)&Asb[(rowbase + mi * 16) * 64 + co[kh]];
}
__device__ __forceinline__ void ldb(const bf16* Bsb, int rowbase,
                                    const int (&co)[2], bf16x8 (&bb)[2][2]) {
#pragma unroll
  for (int ni = 0; ni < 2; ++ni)
#pragma unroll
    for (int kh = 0; kh < 2; ++kh)
      bb[ni][kh] = *(const bf16x8*)&Bsb[(rowbase + ni * 16) * 64 + co[kh]];
}
// kh OUTERMOST: the 8 dependent kh0->kh1 accumulate pairs are separated by 7
// independent MFMAs -> no back-to-back same-acc dependency stalls.
__device__ __forceinline__ void mmq(const bf16x8 (&af)[4][2],
                                    const bf16x8 (&bb)[2][2],
                                    f32x4 (&acc)[8][4], int mh, int nh) {
  __builtin_amdgcn_s_setprio(1);
#pragma unroll
  for (int kh = 0; kh < 2; ++kh)
#pragma unroll
    for (int mi = 0; mi < 4; ++mi)
#pragma unroll
      for (int ni = 0; ni < 2; ++ni)
        acc[mh * 4 + mi][nh * 2 + ni] = __builtin_amdgcn_mfma_f32_16x16x32_bf16(
            af[mi][kh], bb[ni][kh], acc[mh * 4 + mi][nh * 2 + ni], 0, 0, 0);
  __builtin_amdgcn_s_setprio(0);
}

__global__ __launch_bounds__(512, 2) void gemm_fused(
    const bf16* __restrict__ Apack, const bf16* __restrict__ Bm,
    const float* __restrict__ beta, float* __restrict__ out) {
  __shared__ bf16 As[2][256 * 64];
  __shared__ bf16 Bs[2][256 * 64];

  const int t = threadIdx.x;
  const int lane = t & 63;
  const int wv = t >> 6;  // 0..7

  const int id = blockIdx.x;  // 0..255
  const int xcd = id & 7;
  const int lix = id >> 3;  // 0..31
  const int mBase = (xcd * 8 + (lix >> 2)) * 256;  // 64 M-panels
  const int nBase = (lix & 3) * 256;               // 4 N-panels

  // staging source: per-lane row = +(lane>>3), pre-swizzled chunk
  const int sub = lane >> 3;
  const int chunk = (lane & 7) ^ sub;
  const bf16* gA = Apack + (size_t)(mBase + sub) * KTOT + chunk * 8;
  const bf16* gB = Bm + (size_t)(nBase + sub) * KTOT + chunk * 8;

  const int lr = lane & 15;
  const int lq = lane >> 4;
  const int lrm = lr & 7;
  const int waveM = wv & 1;   // 2 M positions x 128 rows
  const int waveN = wv >> 1;  // 4 N positions x 64 cols

  const int co[2] = {(lq ^ lrm) * 8, ((4 + lq) ^ lrm) * 8};
  const int arow = waveM * 128 + lr;
  const int brow = waveN * 64 + lr;

  f32x4 acc[8][4] = {};
  bf16x8 af[4][2], b0[2][2], b1[2][2];

  bf16* As0 = &As[0][0];
  bf16* As1 = &As[1][0];
  bf16* Bs0 = &Bs[0][0];
  bf16* Bs1 = &Bs[1][0];

  // ---- prologue: tile0 (4 units -> buf0), tile1 Am0/Bn0 (-> buf1) ----
  stA(gA, As0, wv, 0, 0);
  stB(gB, Bs0, wv, 0, 0);
  stA(gA, As0, wv, 1, 0);
  stB(gB, Bs0, wv, 1, 0);
  stA(gA, As1, wv, 0, 1);
  stB(gB, Bs1, wv, 0, 1);
  WVM(4);  // tile 0 landed; tile 1's first 2 units in flight
  BARM();
  // window 0: prime frags for tile 0 q00
  lda(As0, arow, co, af);
  ldb(Bs0, brow, co, b0);
  stA(gA, As1, wv, 1, 1);  // Am1(1) -> buf1
  BARM();

  for (int i = 0; i < 10; ++i) {
    const int T1 = 2 * i + 1;
    const int t2 = (T1 + 1 < NKT) ? T1 + 1 : NKT - 1;
    const int t3 = (T1 + 2 < NKT) ? T1 + 2 : NKT - 1;

    // W1: q00(T) | rd B1(buf0) | st Bn1(T+1)->buf1
    mmq(af, b0, acc, 0, 0);
    ldb(Bs0, brow + 32, co, b1);
    stB(gB, Bs1, wv, 1, T1);
    BARM();
    // W2: q01(T) | rd A1(buf0) | st Am0(t2)->buf0
    mmq(af, b1, acc, 0, 1);
    lda(As0, arow + 64, co, af);
    stA(gA, As0, wv, 0, t2);
    BARM();
    // W3: q10(T) | st Bn0(t2)->buf0 | WVM(4): tile T+1 fully landed
    mmq(af, b0, acc, 1, 0);
    stB(gB, Bs0, wv, 0, t2);
    WVM(4);
    BARM();
    // W4: q11(T) | rd A0,B0(buf1) | st Am1(t2)->buf0
    mmq(af, b1, acc, 1, 1);
    lda(As1, arow, co, af);
    ldb(Bs1, brow, co, b0);
    stA(gA, As0, wv, 1, t2);
    BARM();
    // W5: q00(T+1) | rd B1(buf1) | st Bn1(t2)->buf0
    mmq(af, b0, acc, 0, 0);
    ldb(Bs1, brow + 32, co, b1);
    stB(gB, Bs0, wv, 1, t2);
    BARM();
    // W6: q01(T+1) | rd A1(buf1) | st Am0(t3)->buf1
    mmq(af, b1, acc, 0, 1);
    lda(As1, arow + 64, co, af);
    stA(gA, As1, wv, 0, t3);
    BARM();
    // W7: q10(T+1) | st Bn0(t3)->buf1 | WVM(4): tile t2 fully landed
    mmq(af, b0, acc, 1, 0);
    stB(gB, Bs1, wv, 0, t3);
    WVM(4);
    BARM();
    // W8: q11(T+1) | rd A0,B0(buf0 = tile t2) | st Am1(t3)->buf1
    mmq(af, b1, acc, 1, 1);
    lda(As0, arow, co, af);
    ldb(Bs0, brow, co, b0);
    stA(gA, As1, wv, 1, t3);
    BARM();
  }
  WVM(0);  // drain tail re-stages before epilogue

  // Epilogue: C layout col=lane&15, row=lq*4+r. Physical col n: even=re,
  // odd=im of h=n>>1; col parity == lane parity -> shfl_xor(1) pairs them.
  const int col = lane & 15;
  const int row0 = lq * 4;
  const int parity = lane & 1;
#pragma unroll
  for (int nq = 0; nq < 4; ++nq) {
    const int n = nBase + waveN * 64 + nq * 16 + col;
    const float bet = beta[n >> 1];
#pragma unroll
    for (int mq = 0; mq < 8; ++mq) {
      const int mrow = mBase + waveM * 128 + mq * 16 + row0;
#pragma unroll
      for (int r = 0; r < 4; ++r) {
        float a = acc[mq][nq][r];
        float o = __shfl_xor(a, 1);
        float re = parity ? o : a;
        float im = parity ? a : o;
        float mag2 = re * re + im * im;
        float val;
        if (mag2 > 0.f) {
          float rs = __frsqrt_rn(mag2);  // 1/mag
          float s = mag2 * rs + bet;     // mag + beta
          val = (s > 0.f) ? (parity ? im : re) * (s * rs) : 0.f;
        } else {
          val = (bet > 0.f && parity == 0) ? bet : 0.f;  // angle(0)==0
        }
        out[(size_t)(mrow + r) * 1024 + n] = val;
      }
    }
  }
}

// ---------------------------------------------------------------------------
extern "C" void kernel_launch(void* const* d_in, const int* in_sizes, int n_in,
                              void* d_out, int out_size, void* d_ws,
                              size_t ws_size, hipStream_t stream) {
  const float* x = (const float*)d_in[0];
  const float* hxre = (const float*)d_in[1];
  const float* hxim = (const float*)d_in[2];
  const float* ang = (const float*)d_in[3];
  const float* rre = (const float*)d_in[4];
  const float* rim = (const float*)d_in[5];
  const float* wre = (const float*)d_in[6];
  const float* wim = (const float*)d_in[7];
  const float* beta = (const float*)d_in[8];
  const int* perm = (const int*)d_in[9];

  char* ws = (char*)d_ws;
  bf16* Bm = (bf16*)ws;                                 // 1024x1280 bf16, 2.5 MiB
  bf16* Apack = (bf16*)(ws + (size_t)1024 * KTOT * 2);  // 16384x1280 bf16, 40 MiB

  prep<<<512 + (NB * 160) / 256, 256, 0, stream>>>(ang, rre, rim, wre, wim,
                                                   perm, hxre, hxim, x, Bm,
                                                   Apack);
  gemm_fused<<<256, 512, 0, stream>>>(Apack, Bm, beta, (float*)d_out);
}

// Round 6
// 200.477 us; speedup vs baseline: 1.0144x; 1.0040x over previous
//
#include <hip/hip_runtime.h>
#include <hip/hip_bf16.h>
#include <stdint.h>
#include <stddef.h>

typedef __bf16 bf16;
typedef bf16 bf16x8 __attribute__((ext_vector_type(8)));
typedef float f32x4 __attribute__((ext_vector_type(4)));

#define EPSN 1e-8f
#define TWO_PI 6.283185307179586f

#define NB 16384   // batch
#define NH 512     // hidden
#define NI 256     // input
#define KTOT 1280  // 512 + 512 + 256
#define NKT 20     // K-tiles of 64

__device__ __forceinline__ float2 cmul(float2 a, float2 b) {
  return make_float2(a.x * b.x - a.y * b.y, a.x * b.y + a.y * b.x);
}
// a * conj(b)
__device__ __forceinline__ float2 cmulconj(float2 a, float2 b) {
  return make_float2(a.x * b.x + a.y * b.y, a.y * b.x - a.x * b.y);
}
__device__ __forceinline__ float2 cadd(float2 a, float2 b) {
  return make_float2(a.x + b.x, a.y + b.y);
}
__device__ __forceinline__ int brev9(int i) {
  return (int)(__brev((unsigned)i) >> 23);
}

// async global->LDS, 16B per lane; lds dest = wave-uniform base + lane*16
__device__ __forceinline__ void gload16(const bf16* g, bf16* l) {
  __builtin_amdgcn_global_load_lds(
      (const __attribute__((address_space(1))) void*)g,
      (__attribute__((address_space(3))) void*)l, 16, 0, 0);
}

// ---------------------------------------------------------------------------
// prep: unchanged from the verified 200µs kernel.
// blocks [0,512) = build_U column j; blocks [512, 10752) = pack_A octets.
// ---------------------------------------------------------------------------
__global__ __launch_bounds__(256) void prep(
    const float* __restrict__ ang, const float* __restrict__ rre,
    const float* __restrict__ rim, const float* __restrict__ wre,
    const float* __restrict__ wim, const int* __restrict__ perm,
    const float* __restrict__ hxre, const float* __restrict__ hxim,
    const float* __restrict__ x, bf16* __restrict__ Bm,
    bf16* __restrict__ Apack) {
  __shared__ float2 bufA[512];
  __shared__ float2 bufB[512];
  __shared__ float2 redw[4];
  __shared__ float2 bc;
  __shared__ float2 red2[256];

  const int bid = blockIdx.x;
  const int t = threadIdx.x;

  if (bid >= 512) {
    // ---------------- pack_A ----------------
    const int tid = (bid - 512) * 256 + t;  // 0 .. 16384*160-1
    const int b = tid / 160;
    const int o = tid - b * 160;
    const float* src;
    if (o < 64)
      src = hxre + (size_t)b * 512 + o * 8;
    else if (o < 128)
      src = hxim + (size_t)b * 512 + (o - 64) * 8;
    else
      src = x + (size_t)b * 256 + (o - 128) * 8;
    float4 f0 = ((const float4*)src)[0];
    float4 f1 = ((const float4*)src)[1];
    bf16x8 v;
    v[0] = (bf16)f0.x; v[1] = (bf16)f0.y; v[2] = (bf16)f0.z; v[3] = (bf16)f0.w;
    v[4] = (bf16)f1.x; v[5] = (bf16)f1.y; v[6] = (bf16)f1.z; v[7] = (bf16)f1.w;
    *(bf16x8*)(Apack + (size_t)b * KTOT + o * 8) = v;
    return;
  }

  // ---------------- build_U for column j = bid ----------------
  const int j = bid;
  const int j0 = t, j1 = t + 256;

  const float r1x0 = rre[j0], r1y0 = rim[j0];
  const float r1x1 = rre[j1], r1y1 = rim[j1];
  const float r2x0 = rre[512 + j0], r2y0 = rim[512 + j0];
  const float r2x1 = rre[512 + j1], r2y1 = rim[512 + j1];
  red2[t] = make_float2(r1x0 * r1x0 + r1y0 * r1y0 + r1x1 * r1x1 + r1y1 * r1y1,
                        r2x0 * r2x0 + r2y0 * r2y0 + r2x1 * r2x1 + r2y1 * r2y1);
  __syncthreads();
  for (int off = 128; off > 0; off >>= 1) {
    if (t < off) {
      red2[t].x += red2[t + off].x;
      red2[t].y += red2[t + off].y;
    }
    __syncthreads();
  }
  const float inv1 = 1.0f / (sqrtf(red2[0].x) + EPSN);
  const float inv2 = 1.0f / (sqrtf(red2[0].y) + EPSN);
  const float2 v1a = make_float2(r1x0 * inv1, r1y0 * inv1);
  const float2 v1b = make_float2(r1x1 * inv1, r1y1 * inv1);
  const float2 v2a = make_float2(r2x0 * inv2, r2y0 * inv2);
  const float2 v2b = make_float2(r2x1 * inv2, r2y1 * inv2);

  {
    float sj, cj;
    __sincosf(ang[j], &sj, &cj);
    const float2 dj = make_float2(cj, sj);
    float2 z = make_float2(0.f, 0.f);
    bufA[brev9(j0)] = (j0 == j) ? dj : z;
    bufA[brev9(j1)] = (j1 == j) ? dj : z;
  }
  __syncthreads();

#pragma unroll
  for (int st = 0; st < 9; ++st) {
    const int half = 1 << st;
    const int pos = t & (half - 1);
    const int i0 = ((t >> st) << (st + 1)) + pos;
    const int i1 = i0 + half;
    const float angv = -TWO_PI * (float)pos / (float)(2 << st);
    float sn, cs;
    __sincosf(angv, &sn, &cs);
    float2 u = bufA[i0];
    float2 w = bufA[i1];
    float2 tw = make_float2(cs * w.x - sn * w.y, cs * w.y + sn * w.x);
    bufA[i0] = make_float2(u.x + tw.x, u.y + tw.y);
    bufA[i1] = make_float2(u.x - tw.x, u.y - tw.y);
    __syncthreads();
  }

  {
    float2 p = cadd(cmul(bufA[j0], v1a), cmul(bufA[j1], v1b));
    for (int off = 32; off > 0; off >>= 1) {
      p.x += __shfl_down(p.x, off);
      p.y += __shfl_down(p.y, off);
    }
    if ((t & 63) == 0) redw[t >> 6] = p;
    __syncthreads();
    if (t == 0) bc = cadd(cadd(redw[0], redw[1]), cadd(redw[2], redw[3]));
    __syncthreads();
  }
  const float2 dot1 = bc;

  {
    float2 c0 = cmulconj(dot1, v1a);
    float2 c1 = cmulconj(dot1, v1b);
    float2 a0 = bufA[j0], a1 = bufA[j1];
    bufA[j0] = make_float2(a0.x - 2.f * c0.x, a0.y - 2.f * c0.y);
    bufA[j1] = make_float2(a1.x - 2.f * c1.x, a1.y - 2.f * c1.y);
  }
  __syncthreads();

  {
    int p0 = perm[j0], p1 = perm[j1];
    float s0, c0, s1, c1;
    __sincosf(ang[512 + j0], &s0, &c0);
    __sincosf(ang[512 + j1], &s1, &c1);
    float2 g0 = cmul(make_float2(c0, s0), bufA[p0]);
    float2 g1 = cmul(make_float2(c1, s1), bufA[p1]);
    bufB[brev9(j0)] = g0;
    bufB[brev9(j1)] = g1;
  }
  __syncthreads();

#pragma unroll
  for (int st = 0; st < 9; ++st) {
    const int half = 1 << st;
    const int pos = t & (half - 1);
    const int i0 = ((t >> st) << (st + 1)) + pos;
    const int i1 = i0 + half;
    const float angv = TWO_PI * (float)pos / (float)(2 << st);
    float sn, cs;
    __sincosf(angv, &sn, &cs);
    float2 u = bufB[i0];
    float2 w = bufB[i1];
    float2 tw = make_float2(cs * w.x - sn * w.y, cs * w.y + sn * w.x);
    bufB[i0] = make_float2(u.x + tw.x, u.y + tw.y);
    bufB[i1] = make_float2(u.x - tw.x, u.y - tw.y);
    __syncthreads();
  }

  {
    float2 q = cadd(cmul(bufB[j0], v2a), cmul(bufB[j1], v2b));
    for (int off = 32; off > 0; off >>= 1) {
      q.x += __shfl_down(q.x, off);
      q.y += __shfl_down(q.y, off);
    }
    if ((t & 63) == 0) redw[t >> 6] = q;
    __syncthreads();
    if (t == 0) bc = cadd(cadd(redw[0], redw[1]), cadd(redw[2], redw[3]));
    __syncthreads();
  }
  const float invN = 1.0f / 512.0f;
  const float2 dot2 = make_float2(bc.x * invN, bc.y * invN);

#pragma unroll
  for (int e = 0; e < 2; ++e) {
    const int i = (e == 0) ? j0 : j1;
    const float2 vj = (e == 0) ? v2a : v2b;
    float2 h2 = make_float2(bufB[i].x * invN, bufB[i].y * invN);
    float2 c2 = cmulconj(dot2, vj);
    float2 hh = make_float2(h2.x - 2.f * c2.x, h2.y - 2.f * c2.y);
    float s3, c3;
    __sincosf(ang[1024 + i], &s3, &c3);
    float2 u = cmul(make_float2(c3, s3), hh);  // U[i][j]
    bf16* r0 = Bm + (size_t)(2 * i) * KTOT;
    bf16* r1 = Bm + (size_t)(2 * i + 1) * KTOT;
    r0[j] = (bf16)u.x;
    r0[512 + j] = (bf16)(-u.y);
    r1[j] = (bf16)u.y;
    r1[512 + j] = (bf16)u.x;
  }

  Bm[(size_t)(2 * j) * KTOT + 1024 + t] = (bf16)wre[j * NI + t];
  Bm[(size_t)(2 * j + 1) * KTOT + 1024 + t] = (bf16)wim[j * NI + t];
}

// ---------------------------------------------------------------------------
// Fused GEMM + ModReLU — single-barrier windows + T19 forced interleave +
// coalesced LDS-transpose epilogue (round 6).
//
// Round-5 diagnosis: MFMA-phase (~515 cyc/window/CU) and LDS-phase (~700)
// serialize inside each lockstep window (sum matches measured 1500). Fix 1:
// sched_group_barrier {2 MFMA, 2 DS_READ}x8 per window forces compile-time
// interleave of the dependency-free ds_reads into the MFMA burst (T19/CK
// pattern; m196 showed the fine interleave is the lever). Fix 2: epilogue
// WRITE_SIZE was 97.7 MB vs 67 ideal (4B scattered stores, 64B segments).
// Round-trip results through LDS (reuse the 128 KiB staging buffer as
// [128][256] f32, two halves) -> each wave stores 1 KB contiguous rows.
//
// Geometry unchanged: 256x256 tile, BK=64, 8 waves (2Mx4N), 128 KiB LDS
// dbuf, grid 256 = 1 block/CU. Window plan identical to round 5 (verified):
//  W1: q00(T)   rd B1(b0)       st Bn1(T+1)->b1  | BAR
//  W2: q01(T)   rd A1(b0)       st Am0(t2)->b0   | BAR
//  W3: q10(T)                   st Bn0(t2)->b0   | WVM(4) BAR
//  W4: q11(T)   rd A0,B0(b1)    st Am1(t2)->b0   | BAR
//  W5: q00(T+1) rd B1(b1)       st Bn1(t2)->b0   | BAR
//  W6: q01(T+1) rd A1(b1)       st Am0(t3)->b1   | BAR
//  W7: q10(T+1)                 st Bn0(t3)->b1   | WVM(4) BAR
//  W8: q11(T+1) rd A0,B0(b0)    st Am1(t3)->b1   | BAR
// vmcnt never 0 in-loop; tail prefetch clamped to 19 (benign re-stages).
// Barriers: builtin ONLY (inline-asm s_barrier is non-convergent -> deadlock;
// learned rounds 1/3). Swizzle: LDS chunk p of row r holds logical chunk
// p^(r&7); staging pre-swizzles the GLOBAL chunk ((lane&7)^(lane>>3)); reads
// use ((kh*4+lq)^(row&7)) — verified 0-conflict.
// ---------------------------------------------------------------------------

#define BARM() __builtin_amdgcn_s_barrier()
#define WVM(n) asm volatile("s_waitcnt vmcnt(" #n ")" ::: "memory")

// T19: force {2 MFMA, 2 DS_READ} interleave in this scheduling region.
__device__ __forceinline__ void IL() {
#pragma unroll
  for (int g = 0; g < 8; ++g) {
    __builtin_amdgcn_sched_group_barrier(0x008, 2, 0);  // 2 MFMA
    __builtin_amdgcn_sched_group_barrier(0x100, 2, 0);  // 2 DS_READ
  }
}

// stage unit Am(h) of K-tile kt into A-buffer Asb (rows h*64+wv*8 and +128)
__device__ __forceinline__ void stA(const bf16* gA, bf16* Asb, int wv, int h,
                                    int kt) {
  const int r0 = h * 64 + wv * 8;
  const int r1 = r0 + 128;
  gload16(gA + (size_t)r0 * KTOT + kt * 64, Asb + r0 * 64);
  gload16(gA + (size_t)r1 * KTOT + kt * 64, Asb + r1 * 64);
}
// stage unit Bn(h): rows (u>>2)*64 + h*32 + (u&3)*8, u = wv*2+g
__device__ __forceinline__ void stB(const bf16* gB, bf16* Bsb, int wv, int h,
                                    int kt) {
  const int u0 = wv * 2, u1 = u0 + 1;
  const int r0 = (u0 >> 2) * 64 + h * 32 + (u0 & 3) * 8;
  const int r1 = (u1 >> 2) * 64 + h * 32 + (u1 & 3) * 8;
  gload16(gB + (size_t)r0 * KTOT + kt * 64, Bsb + r0 * 64);
  gload16(gB + (size_t)r1 * KTOT + kt * 64, Bsb + r1 * 64);
}

__device__ __forceinline__ void lda(const bf16* Asb, int rowbase,
                                    const int (&co)[2], bf16x8 (&af)[4][2]) {
#pragma unroll
  for (int mi = 0; mi < 4; ++mi)
#pragma unroll
    for (int kh = 0; kh < 2; ++kh)
      af[mi][kh] = *(const bf16x8*)&Asb[(rowbase + mi * 16) * 64 + co[kh]];
}
__device__ __forceinline__ void ldb(const bf16* Bsb, int rowbase,
                                    const int (&co)[2], bf16x8 (&bb)[2][2]) {
#pragma unroll
  for (int ni = 0; ni < 2; ++ni)
#pragma unroll
    for (int kh = 0; kh < 2; ++kh)
      bb[ni][kh] = *(const bf16x8*)&Bsb[(rowbase + ni * 16) * 64 + co[kh]];
}
// kh OUTERMOST: the 8 dependent kh0->kh1 accumulate pairs are separated by 7
// independent MFMAs -> no back-to-back same-acc dependency stalls.
__device__ __forceinline__ void mmq(const bf16x8 (&af)[4][2],
                                    const bf16x8 (&bb)[2][2],
                                    f32x4 (&acc)[8][4], int mh, int nh) {
  __builtin_amdgcn_s_setprio(1);
#pragma unroll
  for (int kh = 0; kh < 2; ++kh)
#pragma unroll
    for (int mi = 0; mi < 4; ++mi)
#pragma unroll
      for (int ni = 0; ni < 2; ++ni)
        acc[mh * 4 + mi][nh * 2 + ni] = __builtin_amdgcn_mfma_f32_16x16x32_bf16(
            af[mi][kh], bb[ni][kh], acc[mh * 4 + mi][nh * 2 + ni], 0, 0, 0);
  __builtin_amdgcn_s_setprio(0);
}

__global__ __launch_bounds__(512, 2) void gemm_fused(
    const bf16* __restrict__ Apack, const bf16* __restrict__ Bm,
    const float* __restrict__ beta, float* __restrict__ out) {
  __shared__ __attribute__((aligned(16))) unsigned char SM[131072];
  bf16* As0 = (bf16*)SM;                  // 256x64 bf16 = 32 KiB
  bf16* As1 = (bf16*)(SM + 32768);
  bf16* Bs0 = (bf16*)(SM + 65536);
  bf16* Bs1 = (bf16*)(SM + 98304);
  float* fbuf = (float*)SM;               // epilogue: [128][256] f32 = 128 KiB

  const int t = threadIdx.x;
  const int lane = t & 63;
  const int wv = t >> 6;  // 0..7

  const int id = blockIdx.x;  // 0..255
  const int xcd = id & 7;
  const int lix = id >> 3;  // 0..31
  const int mBase = (xcd * 8 + (lix >> 2)) * 256;  // 64 M-panels
  const int nBase = (lix & 3) * 256;               // 4 N-panels

  // staging source: per-lane row = +(lane>>3), pre-swizzled chunk
  const int sub = lane >> 3;
  const int chunk = (lane & 7) ^ sub;
  const bf16* gA = Apack + (size_t)(mBase + sub) * KTOT + chunk * 8;
  const bf16* gB = Bm + (size_t)(nBase + sub) * KTOT + chunk * 8;

  const int lr = lane & 15;
  const int lq = lane >> 4;
  const int lrm = lr & 7;
  const int waveM = wv & 1;   // 2 M positions x 128 rows
  const int waveN = wv >> 1;  // 4 N positions x 64 cols

  const int co[2] = {(lq ^ lrm) * 8, ((4 + lq) ^ lrm) * 8};
  const int arow = waveM * 128 + lr;
  const int brow = waveN * 64 + lr;

  f32x4 acc[8][4] = {};
  bf16x8 af[4][2], b0[2][2], b1[2][2];

  // ---- prologue: tile0 (4 units -> buf0), tile1 Am0/Bn0 (-> buf1) ----
  stA(gA, As0, wv, 0, 0);
  stB(gB, Bs0, wv, 0, 0);
  stA(gA, As0, wv, 1, 0);
  stB(gB, Bs0, wv, 1, 0);
  stA(gA, As1, wv, 0, 1);
  stB(gB, Bs1, wv, 0, 1);
  WVM(4);  // tile 0 landed; tile 1's first 2 units in flight
  BARM();
  // window 0: prime frags for tile 0 q00
  lda(As0, arow, co, af);
  ldb(Bs0, brow, co, b0);
  stA(gA, As1, wv, 1, 1);  // Am1(1) -> buf1
  BARM();

  for (int i = 0; i < 10; ++i) {
    const int T1 = 2 * i + 1;
    const int t2 = (T1 + 1 < NKT) ? T1 + 1 : NKT - 1;
    const int t3 = (T1 + 2 < NKT) ? T1 + 2 : NKT - 1;

    // W1: q00(T) | rd B1(buf0) | st Bn1(T+1)->buf1
    mmq(af, b0, acc, 0, 0);
    ldb(Bs0, brow + 32, co, b1);
    stB(gB, Bs1, wv, 1, T1);
    IL();
    BARM();
    // W2: q01(T) | rd A1(buf0) | st Am0(t2)->buf0
    mmq(af, b1, acc, 0, 1);
    lda(As0, arow + 64, co, af);
    stA(gA, As0, wv, 0, t2);
    IL();
    BARM();
    // W3: q10(T) | st Bn0(t2)->buf0 | WVM(4): tile T+1 fully landed
    mmq(af, b0, acc, 1, 0);
    stB(gB, Bs0, wv, 0, t2);
    WVM(4);
    BARM();
    // W4: q11(T) | rd A0,B0(buf1) | st Am1(t2)->buf0
    mmq(af, b1, acc, 1, 1);
    lda(As1, arow, co, af);
    ldb(Bs1, brow, co, b0);
    stA(gA, As0, wv, 1, t2);
    IL();
    BARM();
    // W5: q00(T+1) | rd B1(buf1) | st Bn1(t2)->buf0
    mmq(af, b0, acc, 0, 0);
    ldb(Bs1, brow + 32, co, b1);
    stB(gB, Bs0, wv, 1, t2);
    IL();
    BARM();
    // W6: q01(T+1) | rd A1(buf1) | st Am0(t3)->buf1
    mmq(af, b1, acc, 0, 1);
    lda(As1, arow + 64, co, af);
    stA(gA, As1, wv, 0, t3);
    IL();
    BARM();
    // W7: q10(T+1) | st Bn0(t3)->buf1 | WVM(4): tile t2 fully landed
    mmq(af, b0, acc, 1, 0);
    stB(gB, Bs1, wv, 0, t3);
    WVM(4);
    BARM();
    // W8: q11(T+1) | rd A0,B0(buf0 = tile t2) | st Am1(t3)->buf1
    mmq(af, b1, acc, 1, 1);
    lda(As0, arow, co, af);
    ldb(Bs0, brow, co, b0);
    stA(gA, As1, wv, 1, t3);
    IL();
    BARM();
  }
  WVM(0);  // drain all outstanding stage traffic
  BARM();  // every wave drained -> safe to reuse SM as fbuf

  // ---- coalesced epilogue via LDS transpose (two 128-row halves) ----
  // ModReLU math unchanged: C layout col=lane&15, row=lq*4+r; physical col n
  // even=re, odd=im of h=n>>1; col parity == lane parity -> shfl_xor(1).
  const int col = lane & 15;
  const int parity = lane & 1;
#pragma unroll
  for (int half = 0; half < 2; ++half) {
    if (half) BARM();  // previous half's fbuf fully consumed
    if (waveM == half) {
#pragma unroll
      for (int nq = 0; nq < 4; ++nq) {
        const int cbase = waveN * 64 + nq * 16 + col;
        const float bet = beta[(nBase + cbase) >> 1];
#pragma unroll
        for (int mq = 0; mq < 8; ++mq) {
#pragma unroll
          for (int r = 0; r < 4; ++r) {
            float a = acc[mq][nq][r];
            float o = __shfl_xor(a, 1);
            float re = parity ? o : a;
            float im = parity ? a : o;
            float mag2 = re * re + im * im;
            float val;
            if (mag2 > 0.f) {
              float rs = __frsqrt_rn(mag2);  // 1/mag
              float s = mag2 * rs + bet;     // mag + beta
              val = (s > 0.f) ? (parity ? im : re) * (s * rs) : 0.f;
            } else {
              val = (bet > 0.f && parity == 0) ? bet : 0.f;  // angle(0)==0
            }
            fbuf[(mq * 16 + lq * 4 + r) * 256 + cbase] = val;
          }
        }
      }
    }
    BARM();  // fbuf[half] ready
    // all 8 waves: each stores 16 full rows, 1 KB contiguous per row
#pragma unroll
    for (int rr = 0; rr < 16; ++rr) {
      const int row = wv * 16 + rr;
      const float4 v = ((const float4*)(fbuf + row * 256))[lane];
      ((float4*)(out + (size_t)(mBase + half * 128 + row) * 1024 + nBase))[lane] = v;
    }
  }
}

// ---------------------------------------------------------------------------
extern "C" void kernel_launch(void* const* d_in, const int* in_sizes, int n_in,
                              void* d_out, int out_size, void* d_ws,
                              size_t ws_size, hipStream_t stream) {
  const float* x = (const float*)d_in[0];
  const float* hxre = (const float*)d_in[1];
  const float* hxim = (const float*)d_in[2];
  const float* ang = (const float*)d_in[3];
  const float* rre = (const float*)d_in[4];
  const float* rim = (const float*)d_in[5];
  const float* wre = (const float*)d_in[6];
  const float* wim = (const float*)d_in[7];
  const float* beta = (const float*)d_in[8];
  const int* perm = (const int*)d_in[9];

  char* ws = (char*)d_ws;
  bf16* Bm = (bf16*)ws;                                 // 1024x1280 bf16, 2.5 MiB
  bf16* Apack = (bf16*)(ws + (size_t)1024 * KTOT * 2);  // 16384x1280 bf16, 40 MiB

  prep<<<512 + (NB * 160) / 256, 256, 0, stream>>>(ang, rre, rim, wre, wim,
                                                   perm, hxre, hxim, x, Bm,
                                                   Apack);
  gemm_fused<<<256, 512, 0, stream>>>(Apack, Bm, beta, (float*)d_out);
}

// Round 8
// 197.449 us; speedup vs baseline: 1.0299x; 1.0153x over previous
//
#include <hip/hip_runtime.h>
#include <hip/hip_bf16.h>
#include <stdint.h>
#include <stddef.h>

typedef __bf16 bf16;
typedef bf16 bf16x8 __attribute__((ext_vector_type(8)));
typedef float f32x4 __attribute__((ext_vector_type(4)));

#define EPSN 1e-8f
#define TWO_PI 6.283185307179586f

#define NB 16384   // batch
#define NH 512     // hidden
#define NI 256     // input
#define KTOT 1280  // 512 + 512 + 256
#define NKT 20     // K-tiles of 64

__device__ __forceinline__ float2 cmul(float2 a, float2 b) {
  return make_float2(a.x * b.x - a.y * b.y, a.x * b.y + a.y * b.x);
}
// a * conj(b)
__device__ __forceinline__ float2 cmulconj(float2 a, float2 b) {
  return make_float2(a.x * b.x + a.y * b.y, a.y * b.x - a.x * b.y);
}
__device__ __forceinline__ float2 cadd(float2 a, float2 b) {
  return make_float2(a.x + b.x, a.y + b.y);
}
__device__ __forceinline__ int brev9(int i) {
  return (int)(__brev((unsigned)i) >> 23);
}

// async global->LDS, 16B per lane; lds dest = wave-uniform base + lane*16
__device__ __forceinline__ void gload16(const bf16* g, bf16* l) {
  __builtin_amdgcn_global_load_lds(
      (const __attribute__((address_space(1))) void*)g,
      (__attribute__((address_space(3))) void*)l, 16, 0, 0);
}

// ---------------------------------------------------------------------------
// prep: pack_A branch-free (round 7, resubmitted unchanged — round-7 run
// died in container acquisition with no kernel signal; identical resubmit
// discriminates infra vs kernel).
//   blocks [0,512)              : build_U column j (verified, unchanged)
//   blocks [512, 512+4096)      : hxre -> Apack[.., 0:512)
//   blocks [512+4096, 512+8192) : hxim -> Apack[.., 512:1024)
//   blocks [512+8192, 512+10240): x    -> Apack[.., 1024:1280)
// One wave = one contiguous row-segment (2 KB read / 1 KB write); shifts
// only -> zero divergence, zero integer division.
// ---------------------------------------------------------------------------
__global__ __launch_bounds__(256) void prep(
    const float* __restrict__ ang, const float* __restrict__ rre,
    const float* __restrict__ rim, const float* __restrict__ wre,
    const float* __restrict__ wim, const int* __restrict__ perm,
    const float* __restrict__ hxre, const float* __restrict__ hxim,
    const float* __restrict__ x, bf16* __restrict__ Bm,
    bf16* __restrict__ Apack) {
  __shared__ float2 bufA[512];
  __shared__ float2 bufB[512];
  __shared__ float2 redw[4];
  __shared__ float2 bc;
  __shared__ float2 red2[256];

  const int bid = blockIdx.x;
  const int t = threadIdx.x;

  if (bid >= 512) {
    // ---------------- pack_A (branch-free regions) ----------------
    const float* src;
    bf16* dst;
    if (bid < 512 + 4096) {
      const int tid = (bid - 512) * 256 + t;
      const int b = tid >> 6;            // 64 threads per 512-f32 row
      const int o = (tid & 63) * 8;
      src = hxre + (size_t)b * 512 + o;
      dst = Apack + (size_t)b * KTOT + o;
    } else if (bid < 512 + 8192) {
      const int tid = (bid - 512 - 4096) * 256 + t;
      const int b = tid >> 6;
      const int o = (tid & 63) * 8;
      src = hxim + (size_t)b * 512 + o;
      dst = Apack + (size_t)b * KTOT + 512 + o;
    } else {
      const int tid = (bid - 512 - 8192) * 256 + t;
      const int b = tid >> 5;            // 32 threads per 256-f32 row
      const int o = (tid & 31) * 8;
      src = x + (size_t)b * 256 + o;
      dst = Apack + (size_t)b * KTOT + 1024 + o;
    }
    float4 f0 = ((const float4*)src)[0];
    float4 f1 = ((const float4*)src)[1];
    bf16x8 v;
    v[0] = (bf16)f0.x; v[1] = (bf16)f0.y; v[2] = (bf16)f0.z; v[3] = (bf16)f0.w;
    v[4] = (bf16)f1.x; v[5] = (bf16)f1.y; v[6] = (bf16)f1.z; v[7] = (bf16)f1.w;
    *(bf16x8*)dst = v;
    return;
  }

  // ---------------- build_U for column j = bid (unchanged) ----------------
  const int j = bid;
  const int j0 = t, j1 = t + 256;

  const float r1x0 = rre[j0], r1y0 = rim[j0];
  const float r1x1 = rre[j1], r1y1 = rim[j1];
  const float r2x0 = rre[512 + j0], r2y0 = rim[512 + j0];
  const float r2x1 = rre[512 + j1], r2y1 = rim[512 + j1];
  red2[t] = make_float2(r1x0 * r1x0 + r1y0 * r1y0 + r1x1 * r1x1 + r1y1 * r1y1,
                        r2x0 * r2x0 + r2y0 * r2y0 + r2x1 * r2x1 + r2y1 * r2y1);
  __syncthreads();
  for (int off = 128; off > 0; off >>= 1) {
    if (t < off) {
      red2[t].x += red2[t + off].x;
      red2[t].y += red2[t + off].y;
    }
    __syncthreads();
  }
  const float inv1 = 1.0f / (sqrtf(red2[0].x) + EPSN);
  const float inv2 = 1.0f / (sqrtf(red2[0].y) + EPSN);
  const float2 v1a = make_float2(r1x0 * inv1, r1y0 * inv1);
  const float2 v1b = make_float2(r1x1 * inv1, r1y1 * inv1);
  const float2 v2a = make_float2(r2x0 * inv2, r2y0 * inv2);
  const float2 v2b = make_float2(r2x1 * inv2, r2y1 * inv2);

  {
    float sj, cj;
    __sincosf(ang[j], &sj, &cj);
    const float2 dj = make_float2(cj, sj);
    float2 z = make_float2(0.f, 0.f);
    bufA[brev9(j0)] = (j0 == j) ? dj : z;
    bufA[brev9(j1)] = (j1 == j) ? dj : z;
  }
  __syncthreads();

#pragma unroll
  for (int st = 0; st < 9; ++st) {
    const int half = 1 << st;
    const int pos = t & (half - 1);
    const int i0 = ((t >> st) << (st + 1)) + pos;
    const int i1 = i0 + half;
    const float angv = -TWO_PI * (float)pos / (float)(2 << st);
    float sn, cs;
    __sincosf(angv, &sn, &cs);
    float2 u = bufA[i0];
    float2 w = bufA[i1];
    float2 tw = make_float2(cs * w.x - sn * w.y, cs * w.y + sn * w.x);
    bufA[i0] = make_float2(u.x + tw.x, u.y + tw.y);
    bufA[i1] = make_float2(u.x - tw.x, u.y - tw.y);
    __syncthreads();
  }

  {
    float2 p = cadd(cmul(bufA[j0], v1a), cmul(bufA[j1], v1b));
    for (int off = 32; off > 0; off >>= 1) {
      p.x += __shfl_down(p.x, off);
      p.y += __shfl_down(p.y, off);
    }
    if ((t & 63) == 0) redw[t >> 6] = p;
    __syncthreads();
    if (t == 0) bc = cadd(cadd(redw[0], redw[1]), cadd(redw[2], redw[3]));
    __syncthreads();
  }
  const float2 dot1 = bc;

  {
    float2 c0 = cmulconj(dot1, v1a);
    float2 c1 = cmulconj(dot1, v1b);
    float2 a0 = bufA[j0], a1 = bufA[j1];
    bufA[j0] = make_float2(a0.x - 2.f * c0.x, a0.y - 2.f * c0.y);
    bufA[j1] = make_float2(a1.x - 2.f * c1.x, a1.y - 2.f * c1.y);
  }
  __syncthreads();

  {
    int p0 = perm[j0], p1 = perm[j1];
    float s0, c0, s1, c1;
    __sincosf(ang[512 + j0], &s0, &c0);
    __sincosf(ang[512 + j1], &s1, &c1);
    float2 g0 = cmul(make_float2(c0, s0), bufA[p0]);
    float2 g1 = cmul(make_float2(c1, s1), bufA[p1]);
    bufB[brev9(j0)] = g0;
    bufB[brev9(j1)] = g1;
  }
  __syncthreads();

#pragma unroll
  for (int st = 0; st < 9; ++st) {
    const int half = 1 << st;
    const int pos = t & (half - 1);
    const int i0 = ((t >> st) << (st + 1)) + pos;
    const int i1 = i0 + half;
    const float angv = TWO_PI * (float)pos / (float)(2 << st);
    float sn, cs;
    __sincosf(angv, &sn, &cs);
    float2 u = bufB[i0];
    float2 w = bufB[i1];
    float2 tw = make_float2(cs * w.x - sn * w.y, cs * w.y + sn * w.x);
    bufB[i0] = make_float2(u.x + tw.x, u.y + tw.y);
    bufB[i1] = make_float2(u.x - tw.x, u.y - tw.y);
    __syncthreads();
  }

  {
    float2 q = cadd(cmul(bufB[j0], v2a), cmul(bufB[j1], v2b));
    for (int off = 32; off > 0; off >>= 1) {
      q.x += __shfl_down(q.x, off);
      q.y += __shfl_down(q.y, off);
    }
    if ((t & 63) == 0) redw[t >> 6] = q;
    __syncthreads();
    if (t == 0) bc = cadd(cadd(redw[0], redw[1]), cadd(redw[2], redw[3]));
    __syncthreads();
  }
  const float invN = 1.0f / 512.0f;
  const float2 dot2 = make_float2(bc.x * invN, bc.y * invN);

#pragma unroll
  for (int e = 0; e < 2; ++e) {
    const int i = (e == 0) ? j0 : j1;
    const float2 vj = (e == 0) ? v2a : v2b;
    float2 h2 = make_float2(bufB[i].x * invN, bufB[i].y * invN);
    float2 c2 = cmulconj(dot2, vj);
    float2 hh = make_float2(h2.x - 2.f * c2.x, h2.y - 2.f * c2.y);
    float s3, c3;
    __sincosf(ang[1024 + i], &s3, &c3);
    float2 u = cmul(make_float2(c3, s3), hh);  // U[i][j]
    bf16* r0 = Bm + (size_t)(2 * i) * KTOT;
    bf16* r1 = Bm + (size_t)(2 * i + 1) * KTOT;
    r0[j] = (bf16)u.x;
    r0[512 + j] = (bf16)(-u.y);
    r1[j] = (bf16)u.y;
    r1[512 + j] = (bf16)u.x;
  }

  Bm[(size_t)(2 * j) * KTOT + 1024 + t] = (bf16)wre[j * NI + t];
  Bm[(size_t)(2 * j + 1) * KTOT + 1024 + t] = (bf16)wim[j * NI + t];
}

// ---------------------------------------------------------------------------
// Fused GEMM + ModReLU — 2-blocks/CU TLP regime (round 7, resubmitted
// unchanged). Every 1-block/CU schedule variant (R0,R2,R4,R5,R6) landed
// 64-104 µs: the per-K-tile barrier drain is structural and a SECOND
// resident block is the proven way to hide it (m114 co-scheduling; m97).
//
// Geometry: 128(M)x256(N) tile, BK=64, 512 thr = 8 waves (2M x 4N), per-wave
// 64x64 out = acc[4][4] f32x4 (64 VGPR). LDS single-buffered:
// A[128][64] 16KB + B[256][64] 32KB = 48KB -> 2 blocks/CU (96KB <= 160).
// Grid = (16384/128)x(1024/256) = 512 = exactly 2/CU, one round.
// Loop: { stage (2 A-gloads + 4 B-gloads per wave); __syncthreads()
//         (auto vmcnt(0) drain); frag reads (16 ds_read_b128/wave);
//         32 MFMA; __syncthreads(); }  — builtin syncs only, no asm
// barriers, no setprio (T5 null on lockstep GEMM, m190).
//
// Swizzle (verified 0-conflict, rounds 0-6): LDS chunk p of row r holds
// logical chunk p^(r&7); stage pre-swizzles the GLOBAL chunk
// ((lane&7)^(lane>>3)) — valid since every gload base row ≡ 0 mod 8;
// frag reads use ((kh*4+lq)^(lr&7))*8.
// XCD swizzle: id&7 -> XCD; each XCD owns 16 M-panels (A L2-resident).
// ---------------------------------------------------------------------------
__global__ __launch_bounds__(512, 4) void gemm_fused(
    const bf16* __restrict__ Apack, const bf16* __restrict__ Bm,
    const float* __restrict__ beta, float* __restrict__ out) {
  __shared__ bf16 As[128 * 64];  // 16 KiB
  __shared__ bf16 Bs[256 * 64];  // 32 KiB

  const int t = threadIdx.x;
  const int lane = t & 63;
  const int wv = t >> 6;  // 0..7

  const int id = blockIdx.x;  // 0..511
  const int xcd = id & 7;
  const int lix = id >> 3;  // 0..63
  const int mBase = (xcd * 16 + (lix >> 2)) * 128;  // 128 M-panels
  const int nBase = (lix & 3) * 256;                // 4 N-panels

  // staging source: per-lane row = +(lane>>3), pre-swizzled chunk
  const int sub = lane >> 3;
  const int chunk = (lane & 7) ^ sub;
  const bf16* gA = Apack + (size_t)(mBase + sub) * KTOT + chunk * 8;
  const bf16* gB = Bm + (size_t)(nBase + sub) * KTOT + chunk * 8;

  const int lr = lane & 15;
  const int lq = lane >> 4;
  const int lrm = lr & 7;
  const int waveM = wv & 1;   // 2 M positions x 64 rows
  const int waveN = wv >> 1;  // 4 N positions x 64 cols

  const int co[2] = {(lq ^ lrm) * 8, ((4 + lq) ^ lrm) * 8};
  const int arow = waveM * 64 + lr;
  const int brow = waveN * 64 + lr;

  f32x4 acc[4][4] = {};

  for (int kt = 0; kt < NKT; ++kt) {
    const int ko = kt * 64;
    // stage A rows [wv*16, wv*16+16): 2 gloads
    gload16(gA + (size_t)(wv * 16) * KTOT + ko, As + (wv * 16) * 64);
    gload16(gA + (size_t)(wv * 16 + 8) * KTOT + ko, As + (wv * 16 + 8) * 64);
    // stage B rows [wv*32, wv*32+32): 4 gloads
#pragma unroll
    for (int j = 0; j < 4; ++j)
      gload16(gB + (size_t)(wv * 32 + j * 8) * KTOT + ko,
              Bs + (wv * 32 + j * 8) * 64);
    __syncthreads();  // drains vmcnt(0): tile staged for all waves

    bf16x8 af[4][2], bfr[4][2];
#pragma unroll
    for (int mi = 0; mi < 4; ++mi)
#pragma unroll
      for (int kh = 0; kh < 2; ++kh)
        af[mi][kh] = *(const bf16x8*)&As[(arow + mi * 16) * 64 + co[kh]];
#pragma unroll
    for (int ni = 0; ni < 4; ++ni)
#pragma unroll
      for (int kh = 0; kh < 2; ++kh)
        bfr[ni][kh] = *(const bf16x8*)&Bs[(brow + ni * 16) * 64 + co[kh]];

    // kh outermost: dependent same-acc pairs separated by 15 independents
#pragma unroll
    for (int kh = 0; kh < 2; ++kh)
#pragma unroll
      for (int mi = 0; mi < 4; ++mi)
#pragma unroll
        for (int ni = 0; ni < 4; ++ni)
          acc[mi][ni] = __builtin_amdgcn_mfma_f32_16x16x32_bf16(
              af[mi][kh], bfr[ni][kh], acc[mi][ni], 0, 0, 0);
    __syncthreads();  // all reads done before next stage overwrites
  }

  // Epilogue (R0/R5-verified): C layout col=lane&15, row=lq*4+r. Physical
  // col n: even=re, odd=im of h=n>>1; col parity == lane parity -> shfl_xor.
  const int col = lane & 15;
  const int row0 = lq * 4;
  const int parity = lane & 1;
#pragma unroll
  for (int ni = 0; ni < 4; ++ni) {
    const int n = nBase + waveN * 64 + ni * 16 + col;
    const float bet = beta[n >> 1];
#pragma unroll
    for (int mi = 0; mi < 4; ++mi) {
      const int mrow = mBase + waveM * 64 + mi * 16 + row0;
#pragma unroll
      for (int r = 0; r < 4; ++r) {
        float a = acc[mi][ni][r];
        float o = __shfl_xor(a, 1);
        float re = parity ? o : a;
        float im = parity ? a : o;
        float mag2 = re * re + im * im;
        float val;
        if (mag2 > 0.f) {
          float rs = __frsqrt_rn(mag2);  // 1/mag
          float s = mag2 * rs + bet;     // mag + beta
          val = (s > 0.f) ? (parity ? im : re) * (s * rs) : 0.f;
        } else {
          val = (bet > 0.f && parity == 0) ? bet : 0.f;  // angle(0)==0
        }
        out[(size_t)(mrow + r) * 1024 + n] = val;
      }
    }
  }
}

// ---------------------------------------------------------------------------
extern "C" void kernel_launch(void* const* d_in, const int* in_sizes, int n_in,
                              void* d_out, int out_size, void* d_ws,
                              size_t ws_size, hipStream_t stream) {
  const float* x = (const float*)d_in[0];
  const float* hxre = (const float*)d_in[1];
  const float* hxim = (const float*)d_in[2];
  const float* ang = (const float*)d_in[3];
  const float* rre = (const float*)d_in[4];
  const float* rim = (const float*)d_in[5];
  const float* wre = (const float*)d_in[6];
  const float* wim = (const float*)d_in[7];
  const float* beta = (const float*)d_in[8];
  const int* perm = (const int*)d_in[9];

  char* ws = (char*)d_ws;
  bf16* Bm = (bf16*)ws;                                 // 1024x1280 bf16, 2.5 MiB
  bf16* Apack = (bf16*)(ws + (size_t)1024 * KTOT * 2);  // 16384x1280 bf16, 40 MiB

  prep<<<512 + 4096 + 4096 + 2048, 256, 0, stream>>>(ang, rre, rim, wre, wim,
                                                     perm, hxre, hxim, x, Bm,
                                                     Apack);
  gemm_fused<<<512, 512, 0, stream>>>(Apack, Bm, beta, (float*)d_out);
}